// Round 10
// baseline (224.081 us; speedup 1.0000x reference)
//
#include <hip/hip_runtime.h>
#include <math.h>

#define FFT_N 16384
#define NT 512
#define B_DIM 8
#define H_DIM 256

// Per-wave LDS region, pad 1 float per 32 (R2-proven scheme).
#define REGION 2048
#define RW (REGION + (REGION >> 5))      // 2112 floats per region per plane
#define PAD(x) ((x) + ((x) >> 5))

// Intra-wave LDS fence (verified R7+): one wave's DS ops complete in order.
#define WAVE_LDS_FENCE() do {                                   \
    __builtin_amdgcn_sched_barrier(0);                          \
    asm volatile("s_waitcnt lgkmcnt(0)" ::: "memory");          \
    __builtin_amdgcn_sched_barrier(0);                          \
} while (0)

__device__ __forceinline__ float2 cmul(float2 a, float2 b) {
    return make_float2(a.x * b.x - a.y * b.y, a.x * b.y + a.y * b.x);
}
__device__ __forceinline__ float2 cadd(float2 a, float2 b) { return make_float2(a.x + b.x, a.y + b.y); }
__device__ __forceinline__ float2 csub(float2 a, float2 b) { return make_float2(a.x - b.x, a.y - b.y); }
__device__ __forceinline__ float2 mulnegi(float2 z) { return make_float2(z.y, -z.x); }   // -i*z
__device__ __forceinline__ float2 mulposi(float2 z) { return make_float2(-z.y, z.x); }   // +i*z

// ---- radix-4 butterflies (verified R1..R9) ----
__device__ __forceinline__ void bfly4(float2& a, float2& b, float2& c, float2& d,
                                      float2 w1, float2 w2, float2 w3) {
    float2 apc = cadd(a, c), amc = csub(a, c);
    float2 bpd = cadd(b, d), bmd = csub(b, d);
    float2 nib = mulnegi(bmd);
    a = cadd(apc, bpd);
    b = cmul(csub(apc, bpd), w2);
    c = cmul(cadd(amc, nib), w1);
    d = cmul(csub(amc, nib), w3);
}
__device__ __forceinline__ void bfly4_nw(float2& a, float2& b, float2& c, float2& d) {
    float2 apc = cadd(a, c), amc = csub(a, c);
    float2 bpd = cadd(b, d), bmd = csub(b, d);
    float2 nib = mulnegi(bmd);
    a = cadd(apc, bpd);
    b = csub(apc, bpd);
    c = cadd(amc, nib);
    d = csub(amc, nib);
}
__device__ __forceinline__ void ibfly4(float2& a, float2& b, float2& c, float2& d,
                                       float2 w1t, float2 w2t) {
    float2 w1 = make_float2(w1t.x, -w1t.y);
    float2 w2 = make_float2(w2t.x, -w2t.y);
    float2 bt = cmul(b, w2), dt = cmul(d, w2);
    float2 A = cadd(a, bt), Bb = csub(a, bt);
    float2 C = cadd(c, dt), Dd = csub(c, dt);
    float2 Cw = cmul(C, w1);
    float2 Dw = mulposi(cmul(Dd, w1));
    a = cadd(A, Cw);  c = csub(A, Cw);
    b = cadd(Bb, Dw); d = csub(Bb, Dw);
}
__device__ __forceinline__ void ibfly4_nw(float2& a, float2& b, float2& c, float2& d) {
    float2 A = cadd(a, b), Bb = csub(a, b);
    float2 C = cadd(c, d), Dd = csub(c, d);
    float2 Dw = mulposi(Dd);
    a = cadd(A, C);  c = csub(A, C);
    b = cadd(Bb, Dw); d = csub(Bb, Dw);
}

// ---- g01 half-pass: rh[m] ≡ r[2m+par] of the verified full g01 ----
// stage0 quads j0=2m0+par: (rh[m0],rh[m0+4],rh[m0+8],rh[m0+12]); i = t+512*j0.
// stage1 quads (rh[4a..4a+3]) share one twiddle triple i = (t+512*par)*4.
__device__ __forceinline__ void fwd_g01_half(float2 rh[16], const int t, const int par,
                                             const float2* __restrict__ tw) {
#pragma unroll
    for (int m0 = 0; m0 < 4; ++m0) {
        const int i = t + 512 * par + 1024 * m0;
        bfly4(rh[m0], rh[m0 + 4], rh[m0 + 8], rh[m0 + 12], tw[i], tw[2 * i], tw[3 * i]);
    }
    {
        const int ig = (t + 512 * par) * 4;
        const float2 w1 = tw[ig], w2 = tw[2 * ig], w3 = tw[3 * ig];
#pragma unroll
        for (int a = 0; a < 4; ++a)
            bfly4(rh[4 * a], rh[4 * a + 1], rh[4 * a + 2], rh[4 * a + 3], w1, w2, w3);
    }
}
__device__ __forceinline__ void inv_g01_half(float2 rh[16], const int t, const int par,
                                             const float2* __restrict__ tw) {
    {
        const int ig = (t + 512 * par) * 4;
        const float2 w1 = tw[ig], w2 = tw[2 * ig];
#pragma unroll
        for (int a = 0; a < 4; ++a)
            ibfly4(rh[4 * a], rh[4 * a + 1], rh[4 * a + 2], rh[4 * a + 3], w1, w2);
    }
#pragma unroll
    for (int m0 = 0; m0 < 4; ++m0) {
        const int i = t + 512 * par + 1024 * m0;
        ibfly4(rh[m0], rh[m0 + 4], rh[m0 + 8], rh[m0 + 12], tw[i], tw[2 * i]);
    }
}

// ---- mid half-pass (one s; LDS halves for s=0/1 are disjoint; maps verified R7..R9) ----
//  W1: rh[jj] <-> eloc = 1024*s + 64*jj + l
//  W2: rh[jj] <-> eloc = 1024*s + 64*(l>>2) + 4*jj + (l&3)
//  W3: rh[jj] <-> eloc = 1024*s + 16*l + jj
// fwd: reads W1 from LDS, returns rh in W3 layout.
__device__ __forceinline__ void fwd_mid_half(float2 rh[16], float* ldsx, float* ldsy,
                                             const int w, const int l, const int s,
                                             const float2* __restrict__ tw) {
#pragma unroll
    for (int jj = 0; jj < 16; ++jj) {
        const int a = w * RW + PAD(1024 * s + 64 * jj + l);
        rh[jj].x = ldsx[a]; rh[jj].y = ldsy[a];
    }
    // stage q=256: i1 = 1024*j0 + 16*l
#pragma unroll
    for (int j0 = 0; j0 < 4; ++j0) {
        const int i1 = 1024 * j0 + 16 * l;
        bfly4(rh[j0], rh[j0 + 4], rh[j0 + 8], rh[j0 + 12], tw[i1], tw[2 * i1], tw[3 * i1]);
    }
    // stage q=64: uniform i2 = 64*l
    {
        const int i2 = 64 * l;
        const float2 w1 = tw[i2], w2 = tw[2 * i2], w3 = tw[3 * i2];
#pragma unroll
        for (int g = 0; g < 4; ++g)
            bfly4(rh[4 * g], rh[4 * g + 1], rh[4 * g + 2], rh[4 * g + 3], w1, w2, w3);
    }
    // wave-local exchange W1 -> W2
#pragma unroll
    for (int jj = 0; jj < 16; ++jj) {
        const int a = w * RW + PAD(1024 * s + 64 * jj + l);
        ldsx[a] = rh[jj].x; ldsy[a] = rh[jj].y;
    }
    WAVE_LDS_FENCE();
    {
        const int lo = 64 * (l >> 2) + (l & 3);
#pragma unroll
        for (int jj = 0; jj < 16; ++jj) {
            const int a = w * RW + PAD(1024 * s + lo + 4 * jj);
            rh[jj].x = ldsx[a]; rh[jj].y = ldsy[a];
        }
    }
    // stage q=16: i3 = 1024*j0 + 256*(l&3)
#pragma unroll
    for (int j0 = 0; j0 < 4; ++j0) {
        const int i3 = 1024 * j0 + 256 * (l & 3);
        bfly4(rh[j0], rh[j0 + 4], rh[j0 + 8], rh[j0 + 12], tw[i3], tw[2 * i3], tw[3 * i3]);
    }
    // stage q=4: uniform i4 = 1024*(l&3)
    {
        const int i4 = 1024 * (l & 3);
        const float2 w1 = tw[i4], w2 = tw[2 * i4], w3 = tw[3 * i4];
#pragma unroll
        for (int g = 0; g < 4; ++g)
            bfly4(rh[4 * g], rh[4 * g + 1], rh[4 * g + 2], rh[4 * g + 3], w1, w2, w3);
    }
    // wave-local exchange W2 -> W3
    {
        const int lo = 64 * (l >> 2) + (l & 3);
#pragma unroll
        for (int jj = 0; jj < 16; ++jj) {
            const int a = w * RW + PAD(1024 * s + lo + 4 * jj);
            ldsx[a] = rh[jj].x; ldsy[a] = rh[jj].y;
        }
    }
    WAVE_LDS_FENCE();
#pragma unroll
    for (int jj = 0; jj < 16; ++jj) {
        const int a = w * RW + PAD(1024 * s + 16 * l + jj);
        rh[jj].x = ldsx[a]; rh[jj].y = ldsy[a];
    }
    // stage q=1 (twiddle-free)
#pragma unroll
    for (int g = 0; g < 4; ++g)
        bfly4_nw(rh[4 * g], rh[4 * g + 1], rh[4 * g + 2], rh[4 * g + 3]);
}
// inv: takes rh in W3 layout, leaves W1 layout written to LDS (caller barriers).
__device__ __forceinline__ void inv_mid_half(float2 rh[16], float* ldsx, float* ldsy,
                                             const int w, const int l, const int s,
                                             const float2* __restrict__ tw) {
#pragma unroll
    for (int g = 0; g < 4; ++g)
        ibfly4_nw(rh[4 * g], rh[4 * g + 1], rh[4 * g + 2], rh[4 * g + 3]);
    // W3 -> W2
#pragma unroll
    for (int jj = 0; jj < 16; ++jj) {
        const int a = w * RW + PAD(1024 * s + 16 * l + jj);
        ldsx[a] = rh[jj].x; ldsy[a] = rh[jj].y;
    }
    WAVE_LDS_FENCE();
    {
        const int lo = 64 * (l >> 2) + (l & 3);
#pragma unroll
        for (int jj = 0; jj < 16; ++jj) {
            const int a = w * RW + PAD(1024 * s + lo + 4 * jj);
            rh[jj].x = ldsx[a]; rh[jj].y = ldsy[a];
        }
    }
    // inv q=4 (uniform), then q=16
    {
        const int i4 = 1024 * (l & 3);
        const float2 w1 = tw[i4], w2 = tw[2 * i4];
#pragma unroll
        for (int g = 0; g < 4; ++g)
            ibfly4(rh[4 * g], rh[4 * g + 1], rh[4 * g + 2], rh[4 * g + 3], w1, w2);
    }
#pragma unroll
    for (int j0 = 0; j0 < 4; ++j0) {
        const int i3 = 1024 * j0 + 256 * (l & 3);
        ibfly4(rh[j0], rh[j0 + 4], rh[j0 + 8], rh[j0 + 12], tw[i3], tw[2 * i3]);
    }
    // W2 -> W1
    {
        const int lo = 64 * (l >> 2) + (l & 3);
#pragma unroll
        for (int jj = 0; jj < 16; ++jj) {
            const int a = w * RW + PAD(1024 * s + lo + 4 * jj);
            ldsx[a] = rh[jj].x; ldsy[a] = rh[jj].y;
        }
    }
    WAVE_LDS_FENCE();
#pragma unroll
    for (int jj = 0; jj < 16; ++jj) {
        const int a = w * RW + PAD(1024 * s + 64 * jj + l);
        rh[jj].x = ldsx[a]; rh[jj].y = ldsy[a];
    }
    // inv q=64 (uniform), then q=256
    {
        const int i2 = 64 * l;
        const float2 w1 = tw[i2], w2 = tw[2 * i2];
#pragma unroll
        for (int g = 0; g < 4; ++g)
            ibfly4(rh[4 * g], rh[4 * g + 1], rh[4 * g + 2], rh[4 * g + 3], w1, w2);
    }
#pragma unroll
    for (int j0 = 0; j0 < 4; ++j0) {
        const int i1 = 1024 * j0 + 16 * l;
        ibfly4(rh[j0], rh[j0 + 4], rh[j0 + 8], rh[j0 + 12], tw[i1], tw[2 * i1]);
    }
    // write W1 (region-private); caller issues the workgroup barrier
#pragma unroll
    for (int jj = 0; jj < 16; ++jj) {
        const int a = w * RW + PAD(1024 * s + 64 * jj + l);
        ldsx[a] = rh[jj].x; ldsy[a] = rh[jj].y;
    }
}

__device__ __forceinline__ float ftanh(float x) {
    float e = __expf(2.0f * x);
    return 1.0f - 2.0f * __builtin_amdgcn_rcpf(e + 1.0f);
}

__global__ void twiddle_init(float2* __restrict__ tw) {
    int t = blockIdx.x * blockDim.x + threadIdx.x;
    if (t < FFT_N) {
        float ang = -2.0f * 3.14159265358979323846f * (float)t / (float)FFT_N;
        float sv, cv;
        sincosf(ang, &sv, &cv);
        tw[t] = make_float2(cv, sv);
    }
}

// Forward FFT of (k_h + dh*delta) -> Kf[h], thread-linear W3 order (32t + 16s + jj).
__global__ __launch_bounds__(NT) void kfft_kernel(const float* __restrict__ k,
                                                  const float* __restrict__ D,
                                                  const float2* __restrict__ tw,
                                                  float2* __restrict__ Kf) {
    __shared__ float ldsx[8 * RW];
    __shared__ float ldsy[8 * RW];
    const int h = blockIdx.x;
    const int t = threadIdx.x;
    const int w = t >> 6, l = t & 63;
    const float* krow = k + (size_t)h * FFT_N;
    const float dh = D[h * (H_DIM + 1)];
#pragma unroll
    for (int par = 0; par < 2; ++par) {
        float2 rh[16];
#pragma unroll
        for (int m = 0; m < 16; ++m)
            rh[m] = make_float2(krow[t + 512 * par + 1024 * m], 0.f);
        if (par == 0 && t == 0) rh[0].x += dh;   // fold diag(D) into k's 0th tap
        fwd_g01_half(rh, t, par, tw);
#pragma unroll
        for (int m = 0; m < 16; ++m) {
            const int e = t + 512 * par + 1024 * m;
            const int a = (e >> 11) * RW + PAD(e & 2047);
            ldsx[a] = rh[m].x; ldsy[a] = rh[m].y;
        }
    }
    __syncthreads();
    float4* out4 = (float4*)(Kf + (size_t)h * FFT_N);
#pragma unroll
    for (int s = 0; s < 2; ++s) {
        float2 rh[16];
        fwd_mid_half(rh, ldsx, ldsy, w, l, s, tw);
#pragma unroll
        for (int q = 0; q < 8; ++q)
            out4[16 * t + 8 * s + q] =
                make_float4(rh[2 * q].x, rh[2 * q].y, rh[2 * q + 1].x, rh[2 * q + 1].y);
    }
}

// Batch rows (2p,h) and (2p+1,h) packed as z = u0 + i*u1.
__global__ __launch_bounds__(NT) void conv_kernel(const float* __restrict__ u,
                                                  const float2* __restrict__ tw,
                                                  const float2* __restrict__ Kf,
                                                  float* __restrict__ out) {
    __shared__ float ldsx[8 * RW];
    __shared__ float ldsy[8 * RW];
    // XCD-chunked bijection (1024 blocks, 1024%8==0)
    const int raw = blockIdx.x;
    const int vb = ((raw & 7) << 7) + (raw >> 3);
    const int h = vb >> 2;
    const int p = vb & 3;
    const int t = threadIdx.x;
    const int w = t >> 6, l = t & 63;
    const size_t row0 = ((size_t)(2 * p) * H_DIM + h) * FFT_N;
    const size_t row1 = row0 + (size_t)H_DIM * FFT_N;
    const float* u0 = u + row0;
    const float* u1 = u + row1;

    // forward: two independent 16-register half-passes (even/odd j)
#pragma unroll
    for (int par = 0; par < 2; ++par) {
        float2 rh[16];
#pragma unroll
        for (int m = 0; m < 16; ++m) {
            const int n = t + 512 * par + 1024 * m;
            rh[m] = make_float2(u0[n], u1[n]);
        }
        fwd_g01_half(rh, t, par, tw);
#pragma unroll
        for (int m = 0; m < 16; ++m) {
            const int e = t + 512 * par + 1024 * m;
            const int a = (e >> 11) * RW + PAD(e & 2047);
            ldsx[a] = rh[m].x; ldsy[a] = rh[m].y;
        }
    }
    __syncthreads();

    // middle: per-s half (LDS halves disjoint), incl. pointwise multiply
    const float4* kf4 = (const float4*)(Kf + (size_t)h * FFT_N);
    const float invN = 1.0f / (float)FFT_N;
#pragma unroll
    for (int s = 0; s < 2; ++s) {
        float2 rh[16];
        fwd_mid_half(rh, ldsx, ldsy, w, l, s, tw);
#pragma unroll
        for (int q = 0; q < 8; ++q) {
            const float4 kw = kf4[16 * t + 8 * s + q];
            const float2 z0 = rh[2 * q], z1 = rh[2 * q + 1];
            rh[2 * q]     = make_float2((z0.x * kw.x - z0.y * kw.y) * invN,
                                        (z0.x * kw.y + z0.y * kw.x) * invN);
            rh[2 * q + 1] = make_float2((z1.x * kw.z - z1.y * kw.w) * invN,
                                        (z1.x * kw.w + z1.y * kw.z) * invN);
        }
        inv_mid_half(rh, ldsx, ldsy, w, l, s, tw);
    }
    __syncthreads();

    // exit: per-parity half-passes
    float* o0 = out + row0;
    float* o1 = out + row1;
#pragma unroll
    for (int par = 0; par < 2; ++par) {
        float2 rh[16];
#pragma unroll
        for (int m = 0; m < 16; ++m) {
            const int e = t + 512 * par + 1024 * m;
            const int a = (e >> 11) * RW + PAD(e & 2047);
            rh[m].x = ldsx[a]; rh[m].y = ldsy[a];
        }
        inv_g01_half(rh, t, par, tw);
#pragma unroll
        for (int m = 0; m < 16; ++m) {
            const int n = t + 512 * par + 1024 * m;
            o0[n] = ftanh(rh[m].x);
            o1[n] = ftanh(rh[m].y);
        }
    }
}

extern "C" void kernel_launch(void* const* d_in, const int* in_sizes, int n_in,
                              void* d_out, int out_size, void* d_ws, size_t ws_size,
                              hipStream_t stream) {
    const float* u = (const float*)d_in[0];   // (B,H,L) f32
    const float* k = (const float*)d_in[1];   // (H,L)   f32
    const float* D = (const float*)d_in[2];   // (H,H)   f32
    float* out = (float*)d_out;

    float2* tw = (float2*)d_ws;               // 16384 float2 = 128 KiB
    float2* Kf = tw + FFT_N;                  // 256*16384 float2 = 32 MiB

    twiddle_init<<<FFT_N / 256, 256, 0, stream>>>(tw);
    kfft_kernel<<<H_DIM, NT, 0, stream>>>(k, D, tw, Kf);
    conv_kernel<<<(B_DIM / 2) * H_DIM, NT, 0, stream>>>(u, tw, Kf, out);
}

// Round 11
// 200.368 us; speedup vs baseline: 1.1183x; 1.1183x over previous
//
#include <hip/hip_runtime.h>
#include <math.h>

#define FFT_N 16384
#define NT 512
#define B_DIM 8
#define H_DIM 256

// Per-wave LDS region, pad 1 float per 32 (R2-proven scheme).
#define REGION 2048
#define RW (REGION + (REGION >> 5))      // 2112 floats per region per plane
#define PAD(x) ((x) + ((x) >> 5))

// Intra-wave LDS fence (verified R7+).
#define WAVE_LDS_FENCE() do {                                   \
    __builtin_amdgcn_sched_barrier(0);                          \
    asm volatile("s_waitcnt lgkmcnt(0)" ::: "memory");          \
    __builtin_amdgcn_sched_barrier(0);                          \
} while (0)

__device__ __forceinline__ float2 cmul(float2 a, float2 b) {
    return make_float2(a.x * b.x - a.y * b.y, a.x * b.y + a.y * b.x);
}
__device__ __forceinline__ float2 cadd(float2 a, float2 b) { return make_float2(a.x + b.x, a.y + b.y); }
__device__ __forceinline__ float2 csub(float2 a, float2 b) { return make_float2(a.x - b.x, a.y - b.y); }
__device__ __forceinline__ float2 mulnegi(float2 z) { return make_float2(z.y, -z.x); }   // -i*z
__device__ __forceinline__ float2 mulposi(float2 z) { return make_float2(-z.y, z.x); }   // +i*z

// ---- radix-4 butterflies (verified R1..R10) ----
__device__ __forceinline__ void bfly4(float2& a, float2& b, float2& c, float2& d,
                                      float2 w1, float2 w2, float2 w3) {
    float2 apc = cadd(a, c), amc = csub(a, c);
    float2 bpd = cadd(b, d), bmd = csub(b, d);
    float2 nib = mulnegi(bmd);
    a = cadd(apc, bpd);
    b = cmul(csub(apc, bpd), w2);
    c = cmul(cadd(amc, nib), w1);
    d = cmul(csub(amc, nib), w3);
}
__device__ __forceinline__ void bfly4_nw(float2& a, float2& b, float2& c, float2& d) {
    float2 apc = cadd(a, c), amc = csub(a, c);
    float2 bpd = cadd(b, d), bmd = csub(b, d);
    float2 nib = mulnegi(bmd);
    a = cadd(apc, bpd);
    b = csub(apc, bpd);
    c = cadd(amc, nib);
    d = csub(amc, nib);
}
__device__ __forceinline__ void ibfly4(float2& a, float2& b, float2& c, float2& d,
                                       float2 w1t, float2 w2t) {
    float2 w1 = make_float2(w1t.x, -w1t.y);
    float2 w2 = make_float2(w2t.x, -w2t.y);
    float2 bt = cmul(b, w2), dt = cmul(d, w2);
    float2 A = cadd(a, bt), Bb = csub(a, bt);
    float2 C = cadd(c, dt), Dd = csub(c, dt);
    float2 Cw = cmul(C, w1);
    float2 Dw = mulposi(cmul(Dd, w1));
    a = cadd(A, Cw);  c = csub(A, Cw);
    b = cadd(Bb, Dw); d = csub(Bb, Dw);
}
__device__ __forceinline__ void ibfly4_nw(float2& a, float2& b, float2& c, float2& d) {
    float2 A = cadd(a, b), Bb = csub(a, b);
    float2 C = cadd(c, d), Dd = csub(c, d);
    float2 Dw = mulposi(Dd);
    a = cadd(A, C);  c = csub(A, C);
    b = cadd(Bb, Dw); d = csub(Bb, Dw);
}

// ---- g01 half-passes (verified R10) ----
__device__ __forceinline__ void fwd_g01_half(float2 rh[16], const int t, const int par,
                                             const float2* __restrict__ tw) {
#pragma unroll
    for (int m0 = 0; m0 < 4; ++m0) {
        const int i = t + 512 * par + 1024 * m0;
        bfly4(rh[m0], rh[m0 + 4], rh[m0 + 8], rh[m0 + 12], tw[i], tw[2 * i], tw[3 * i]);
    }
    {
        const int ig = (t + 512 * par) * 4;
        const float2 w1 = tw[ig], w2 = tw[2 * ig], w3 = tw[3 * ig];
#pragma unroll
        for (int a = 0; a < 4; ++a)
            bfly4(rh[4 * a], rh[4 * a + 1], rh[4 * a + 2], rh[4 * a + 3], w1, w2, w3);
    }
}
__device__ __forceinline__ void inv_g01_half(float2 rh[16], const int t, const int par,
                                             const float2* __restrict__ tw) {
    {
        const int ig = (t + 512 * par) * 4;
        const float2 w1 = tw[ig], w2 = tw[2 * ig];
#pragma unroll
        for (int a = 0; a < 4; ++a)
            ibfly4(rh[4 * a], rh[4 * a + 1], rh[4 * a + 2], rh[4 * a + 3], w1, w2);
    }
#pragma unroll
    for (int m0 = 0; m0 < 4; ++m0) {
        const int i = t + 512 * par + 1024 * m0;
        ibfly4(rh[m0], rh[m0 + 4], rh[m0 + 8], rh[m0 + 12], tw[i], tw[2 * i]);
    }
}

// ---- per-s mid half (kfft only; verified R10) ----
__device__ __forceinline__ void fwd_mid_half(float2 rh[16], float* ldsx, float* ldsy,
                                             const int w, const int l, const int s,
                                             const float2* __restrict__ tw) {
#pragma unroll
    for (int jj = 0; jj < 16; ++jj) {
        const int a = w * RW + PAD(1024 * s + 64 * jj + l);
        rh[jj].x = ldsx[a]; rh[jj].y = ldsy[a];
    }
#pragma unroll
    for (int j0 = 0; j0 < 4; ++j0) {
        const int i1 = 1024 * j0 + 16 * l;
        bfly4(rh[j0], rh[j0 + 4], rh[j0 + 8], rh[j0 + 12], tw[i1], tw[2 * i1], tw[3 * i1]);
    }
    {
        const int i2 = 64 * l;
        const float2 w1 = tw[i2], w2 = tw[2 * i2], w3 = tw[3 * i2];
#pragma unroll
        for (int g = 0; g < 4; ++g)
            bfly4(rh[4 * g], rh[4 * g + 1], rh[4 * g + 2], rh[4 * g + 3], w1, w2, w3);
    }
#pragma unroll
    for (int jj = 0; jj < 16; ++jj) {
        const int a = w * RW + PAD(1024 * s + 64 * jj + l);
        ldsx[a] = rh[jj].x; ldsy[a] = rh[jj].y;
    }
    WAVE_LDS_FENCE();
    {
        const int lo = 64 * (l >> 2) + (l & 3);
#pragma unroll
        for (int jj = 0; jj < 16; ++jj) {
            const int a = w * RW + PAD(1024 * s + lo + 4 * jj);
            rh[jj].x = ldsx[a]; rh[jj].y = ldsy[a];
        }
    }
#pragma unroll
    for (int j0 = 0; j0 < 4; ++j0) {
        const int i3 = 1024 * j0 + 256 * (l & 3);
        bfly4(rh[j0], rh[j0 + 4], rh[j0 + 8], rh[j0 + 12], tw[i3], tw[2 * i3], tw[3 * i3]);
    }
    {
        const int i4 = 1024 * (l & 3);
        const float2 w1 = tw[i4], w2 = tw[2 * i4], w3 = tw[3 * i4];
#pragma unroll
        for (int g = 0; g < 4; ++g)
            bfly4(rh[4 * g], rh[4 * g + 1], rh[4 * g + 2], rh[4 * g + 3], w1, w2, w3);
    }
    {
        const int lo = 64 * (l >> 2) + (l & 3);
#pragma unroll
        for (int jj = 0; jj < 16; ++jj) {
            const int a = w * RW + PAD(1024 * s + lo + 4 * jj);
            ldsx[a] = rh[jj].x; ldsy[a] = rh[jj].y;
        }
    }
    WAVE_LDS_FENCE();
#pragma unroll
    for (int jj = 0; jj < 16; ++jj) {
        const int a = w * RW + PAD(1024 * s + 16 * l + jj);
        rh[jj].x = ldsx[a]; rh[jj].y = ldsy[a];
    }
#pragma unroll
    for (int g = 0; g < 4; ++g)
        bfly4_nw(rh[4 * g], rh[4 * g + 1], rh[4 * g + 2], rh[4 * g + 3]);
}

// ---- conv fused middle: both s-halves, shared twiddles, shared fences ----
// Byte-identical math to R10's per-s code with 1024*s expanded to {0,1024}.
__device__ __forceinline__ void conv_mid_fused(float* ldsx, float* ldsy,
                                               const int t, const int w, const int l,
                                               const float4* __restrict__ kf4,
                                               const float invN,
                                               const float2* __restrict__ tw) {
    float2 r0[16], r1[16];
#pragma unroll
    for (int jj = 0; jj < 16; ++jj) {
        const int a0 = w * RW + PAD(64 * jj + l);
        const int a1 = w * RW + PAD(1024 + 64 * jj + l);
        r0[jj].x = ldsx[a0]; r0[jj].y = ldsy[a0];
        r1[jj].x = ldsx[a1]; r1[jj].y = ldsy[a1];
    }
    // fwd stage q=256
#pragma unroll
    for (int j0 = 0; j0 < 4; ++j0) {
        const int i1 = 1024 * j0 + 16 * l;
        const float2 w1 = tw[i1], w2 = tw[2 * i1], w3 = tw[3 * i1];
        bfly4(r0[j0], r0[j0 + 4], r0[j0 + 8], r0[j0 + 12], w1, w2, w3);
        bfly4(r1[j0], r1[j0 + 4], r1[j0 + 8], r1[j0 + 12], w1, w2, w3);
    }
    // fwd stage q=64 (uniform)
    {
        const int i2 = 64 * l;
        const float2 w1 = tw[i2], w2 = tw[2 * i2], w3 = tw[3 * i2];
#pragma unroll
        for (int g = 0; g < 4; ++g) {
            bfly4(r0[4 * g], r0[4 * g + 1], r0[4 * g + 2], r0[4 * g + 3], w1, w2, w3);
            bfly4(r1[4 * g], r1[4 * g + 1], r1[4 * g + 2], r1[4 * g + 3], w1, w2, w3);
        }
    }
    // W1 -> W2 (one fence for both s)
#pragma unroll
    for (int jj = 0; jj < 16; ++jj) {
        const int a0 = w * RW + PAD(64 * jj + l);
        const int a1 = w * RW + PAD(1024 + 64 * jj + l);
        ldsx[a0] = r0[jj].x; ldsy[a0] = r0[jj].y;
        ldsx[a1] = r1[jj].x; ldsy[a1] = r1[jj].y;
    }
    WAVE_LDS_FENCE();
    {
        const int lo = 64 * (l >> 2) + (l & 3);
#pragma unroll
        for (int jj = 0; jj < 16; ++jj) {
            const int a0 = w * RW + PAD(lo + 4 * jj);
            const int a1 = w * RW + PAD(1024 + lo + 4 * jj);
            r0[jj].x = ldsx[a0]; r0[jj].y = ldsy[a0];
            r1[jj].x = ldsx[a1]; r1[jj].y = ldsy[a1];
        }
    }
    // fwd stage q=16
#pragma unroll
    for (int j0 = 0; j0 < 4; ++j0) {
        const int i3 = 1024 * j0 + 256 * (l & 3);
        const float2 w1 = tw[i3], w2 = tw[2 * i3], w3 = tw[3 * i3];
        bfly4(r0[j0], r0[j0 + 4], r0[j0 + 8], r0[j0 + 12], w1, w2, w3);
        bfly4(r1[j0], r1[j0 + 4], r1[j0 + 8], r1[j0 + 12], w1, w2, w3);
    }
    // fwd stage q=4 (uniform)
    {
        const int i4 = 1024 * (l & 3);
        const float2 w1 = tw[i4], w2 = tw[2 * i4], w3 = tw[3 * i4];
#pragma unroll
        for (int g = 0; g < 4; ++g) {
            bfly4(r0[4 * g], r0[4 * g + 1], r0[4 * g + 2], r0[4 * g + 3], w1, w2, w3);
            bfly4(r1[4 * g], r1[4 * g + 1], r1[4 * g + 2], r1[4 * g + 3], w1, w2, w3);
        }
    }
    // W2 -> W3
    {
        const int lo = 64 * (l >> 2) + (l & 3);
#pragma unroll
        for (int jj = 0; jj < 16; ++jj) {
            const int a0 = w * RW + PAD(lo + 4 * jj);
            const int a1 = w * RW + PAD(1024 + lo + 4 * jj);
            ldsx[a0] = r0[jj].x; ldsy[a0] = r0[jj].y;
            ldsx[a1] = r1[jj].x; ldsy[a1] = r1[jj].y;
        }
    }
    WAVE_LDS_FENCE();
#pragma unroll
    for (int jj = 0; jj < 16; ++jj) {
        const int a0 = w * RW + PAD(16 * l + jj);
        const int a1 = w * RW + PAD(1024 + 16 * l + jj);
        r0[jj].x = ldsx[a0]; r0[jj].y = ldsy[a0];
        r1[jj].x = ldsx[a1]; r1[jj].y = ldsy[a1];
    }
    // fwd stage q=1
#pragma unroll
    for (int g = 0; g < 4; ++g) {
        bfly4_nw(r0[4 * g], r0[4 * g + 1], r0[4 * g + 2], r0[4 * g + 3]);
        bfly4_nw(r1[4 * g], r1[4 * g + 1], r1[4 * g + 2], r1[4 * g + 3]);
    }
    // pointwise multiply (thread-linear W3 order, matches kfft) + 1/N
#pragma unroll
    for (int q = 0; q < 8; ++q) {
        const float4 k0 = kf4[16 * t + q];
        const float4 k1 = kf4[16 * t + 8 + q];
        float2 z;
        z = r0[2 * q];
        r0[2 * q]     = make_float2((z.x * k0.x - z.y * k0.y) * invN, (z.x * k0.y + z.y * k0.x) * invN);
        z = r0[2 * q + 1];
        r0[2 * q + 1] = make_float2((z.x * k0.z - z.y * k0.w) * invN, (z.x * k0.w + z.y * k0.z) * invN);
        z = r1[2 * q];
        r1[2 * q]     = make_float2((z.x * k1.x - z.y * k1.y) * invN, (z.x * k1.y + z.y * k1.x) * invN);
        z = r1[2 * q + 1];
        r1[2 * q + 1] = make_float2((z.x * k1.z - z.y * k1.w) * invN, (z.x * k1.w + z.y * k1.z) * invN);
    }
    // inv stage q=1
#pragma unroll
    for (int g = 0; g < 4; ++g) {
        ibfly4_nw(r0[4 * g], r0[4 * g + 1], r0[4 * g + 2], r0[4 * g + 3]);
        ibfly4_nw(r1[4 * g], r1[4 * g + 1], r1[4 * g + 2], r1[4 * g + 3]);
    }
    // W3 -> W2
#pragma unroll
    for (int jj = 0; jj < 16; ++jj) {
        const int a0 = w * RW + PAD(16 * l + jj);
        const int a1 = w * RW + PAD(1024 + 16 * l + jj);
        ldsx[a0] = r0[jj].x; ldsy[a0] = r0[jj].y;
        ldsx[a1] = r1[jj].x; ldsy[a1] = r1[jj].y;
    }
    WAVE_LDS_FENCE();
    {
        const int lo = 64 * (l >> 2) + (l & 3);
#pragma unroll
        for (int jj = 0; jj < 16; ++jj) {
            const int a0 = w * RW + PAD(lo + 4 * jj);
            const int a1 = w * RW + PAD(1024 + lo + 4 * jj);
            r0[jj].x = ldsx[a0]; r0[jj].y = ldsy[a0];
            r1[jj].x = ldsx[a1]; r1[jj].y = ldsy[a1];
        }
    }
    // inv stage q=4 (uniform), then q=16
    {
        const int i4 = 1024 * (l & 3);
        const float2 w1 = tw[i4], w2 = tw[2 * i4];
#pragma unroll
        for (int g = 0; g < 4; ++g) {
            ibfly4(r0[4 * g], r0[4 * g + 1], r0[4 * g + 2], r0[4 * g + 3], w1, w2);
            ibfly4(r1[4 * g], r1[4 * g + 1], r1[4 * g + 2], r1[4 * g + 3], w1, w2);
        }
    }
#pragma unroll
    for (int j0 = 0; j0 < 4; ++j0) {
        const int i3 = 1024 * j0 + 256 * (l & 3);
        const float2 w1 = tw[i3], w2 = tw[2 * i3];
        ibfly4(r0[j0], r0[j0 + 4], r0[j0 + 8], r0[j0 + 12], w1, w2);
        ibfly4(r1[j0], r1[j0 + 4], r1[j0 + 8], r1[j0 + 12], w1, w2);
    }
    // W2 -> W1
    {
        const int lo = 64 * (l >> 2) + (l & 3);
#pragma unroll
        for (int jj = 0; jj < 16; ++jj) {
            const int a0 = w * RW + PAD(lo + 4 * jj);
            const int a1 = w * RW + PAD(1024 + lo + 4 * jj);
            ldsx[a0] = r0[jj].x; ldsy[a0] = r0[jj].y;
            ldsx[a1] = r1[jj].x; ldsy[a1] = r1[jj].y;
        }
    }
    WAVE_LDS_FENCE();
#pragma unroll
    for (int jj = 0; jj < 16; ++jj) {
        const int a0 = w * RW + PAD(64 * jj + l);
        const int a1 = w * RW + PAD(1024 + 64 * jj + l);
        r0[jj].x = ldsx[a0]; r0[jj].y = ldsy[a0];
        r1[jj].x = ldsx[a1]; r1[jj].y = ldsy[a1];
    }
    // inv stage q=64 (uniform), then q=256
    {
        const int i2 = 64 * l;
        const float2 w1 = tw[i2], w2 = tw[2 * i2];
#pragma unroll
        for (int g = 0; g < 4; ++g) {
            ibfly4(r0[4 * g], r0[4 * g + 1], r0[4 * g + 2], r0[4 * g + 3], w1, w2);
            ibfly4(r1[4 * g], r1[4 * g + 1], r1[4 * g + 2], r1[4 * g + 3], w1, w2);
        }
    }
#pragma unroll
    for (int j0 = 0; j0 < 4; ++j0) {
        const int i1 = 1024 * j0 + 16 * l;
        const float2 w1 = tw[i1], w2 = tw[2 * i1];
        ibfly4(r0[j0], r0[j0 + 4], r0[j0 + 8], r0[j0 + 12], w1, w2);
        ibfly4(r1[j0], r1[j0 + 4], r1[j0 + 8], r1[j0 + 12], w1, w2);
    }
    // write W1 both (caller issues workgroup barrier)
#pragma unroll
    for (int jj = 0; jj < 16; ++jj) {
        const int a0 = w * RW + PAD(64 * jj + l);
        const int a1 = w * RW + PAD(1024 + 64 * jj + l);
        ldsx[a0] = r0[jj].x; ldsy[a0] = r0[jj].y;
        ldsx[a1] = r1[jj].x; ldsy[a1] = r1[jj].y;
    }
}

__device__ __forceinline__ float ftanh(float x) {
    float e = __expf(2.0f * x);
    return 1.0f - 2.0f * __builtin_amdgcn_rcpf(e + 1.0f);
}

__global__ void twiddle_init(float2* __restrict__ tw) {
    int t = blockIdx.x * blockDim.x + threadIdx.x;
    if (t < FFT_N) {
        float ang = -2.0f * 3.14159265358979323846f * (float)t / (float)FFT_N;
        float sv, cv;
        sincosf(ang, &sv, &cv);
        tw[t] = make_float2(cv, sv);
    }
}

// Forward FFT of (k_h + dh*delta) -> Kf[h], thread-linear W3 order (verified R10).
__global__ __launch_bounds__(NT) void kfft_kernel(const float* __restrict__ k,
                                                  const float* __restrict__ D,
                                                  const float2* __restrict__ tw,
                                                  float2* __restrict__ Kf) {
    __shared__ float ldsx[8 * RW];
    __shared__ float ldsy[8 * RW];
    const int h = blockIdx.x;
    const int t = threadIdx.x;
    const int w = t >> 6, l = t & 63;
    const float* krow = k + (size_t)h * FFT_N;
    const float dh = D[h * (H_DIM + 1)];
#pragma unroll
    for (int par = 0; par < 2; ++par) {
        float2 rh[16];
#pragma unroll
        for (int m = 0; m < 16; ++m)
            rh[m] = make_float2(krow[t + 512 * par + 1024 * m], 0.f);
        if (par == 0 && t == 0) rh[0].x += dh;
        fwd_g01_half(rh, t, par, tw);
#pragma unroll
        for (int m = 0; m < 16; ++m) {
            const int e = t + 512 * par + 1024 * m;
            const int a = (e >> 11) * RW + PAD(e & 2047);
            ldsx[a] = rh[m].x; ldsy[a] = rh[m].y;
        }
    }
    __syncthreads();
    float4* out4 = (float4*)(Kf + (size_t)h * FFT_N);
#pragma unroll
    for (int s = 0; s < 2; ++s) {
        float2 rh[16];
        fwd_mid_half(rh, ldsx, ldsy, w, l, s, tw);
#pragma unroll
        for (int q = 0; q < 8; ++q)
            out4[16 * t + 8 * s + q] =
                make_float4(rh[2 * q].x, rh[2 * q].y, rh[2 * q + 1].x, rh[2 * q + 1].y);
    }
}

// Batch rows (2p,h) and (2p+1,h) packed as z = u0 + i*u1.
__global__ __launch_bounds__(NT) void conv_kernel(const float* __restrict__ u,
                                                  const float2* __restrict__ tw,
                                                  const float2* __restrict__ Kf,
                                                  float* __restrict__ out) {
    __shared__ float ldsx[8 * RW];
    __shared__ float ldsy[8 * RW];
    const int raw = blockIdx.x;
    const int vb = ((raw & 7) << 7) + (raw >> 3);   // XCD-chunked bijection
    const int h = vb >> 2;
    const int p = vb & 3;
    const int t = threadIdx.x;
    const int w = t >> 6, l = t & 63;
    const size_t row0 = ((size_t)(2 * p) * H_DIM + h) * FFT_N;
    const size_t row1 = row0 + (size_t)H_DIM * FFT_N;
    const float* u0 = u + row0;
    const float* u1 = u + row1;

    // entry: two independent 16-register half-passes (spill-free, verified R10)
#pragma unroll
    for (int par = 0; par < 2; ++par) {
        float2 rh[16];
#pragma unroll
        for (int m = 0; m < 16; ++m) {
            const int n = t + 512 * par + 1024 * m;
            rh[m] = make_float2(u0[n], u1[n]);
        }
        fwd_g01_half(rh, t, par, tw);
#pragma unroll
        for (int m = 0; m < 16; ++m) {
            const int e = t + 512 * par + 1024 * m;
            const int a = (e >> 11) * RW + PAD(e & 2047);
            ldsx[a] = rh[m].x; ldsy[a] = rh[m].y;
        }
    }
    __syncthreads();

    // fused full-width middle (fwd + pointwise + inv), 4 shared fences
    conv_mid_fused(ldsx, ldsy, t, w, l,
                   (const float4*)(Kf + (size_t)h * FFT_N), 1.0f / (float)FFT_N, tw);
    __syncthreads();

    // exit: per-parity half-passes
    float* o0 = out + row0;
    float* o1 = out + row1;
#pragma unroll
    for (int par = 0; par < 2; ++par) {
        float2 rh[16];
#pragma unroll
        for (int m = 0; m < 16; ++m) {
            const int e = t + 512 * par + 1024 * m;
            const int a = (e >> 11) * RW + PAD(e & 2047);
            rh[m].x = ldsx[a]; rh[m].y = ldsy[a];
        }
        inv_g01_half(rh, t, par, tw);
#pragma unroll
        for (int m = 0; m < 16; ++m) {
            const int n = t + 512 * par + 1024 * m;
            o0[n] = ftanh(rh[m].x);
            o1[n] = ftanh(rh[m].y);
        }
    }
}

extern "C" void kernel_launch(void* const* d_in, const int* in_sizes, int n_in,
                              void* d_out, int out_size, void* d_ws, size_t ws_size,
                              hipStream_t stream) {
    const float* u = (const float*)d_in[0];   // (B,H,L) f32
    const float* k = (const float*)d_in[1];   // (H,L)   f32
    const float* D = (const float*)d_in[2];   // (H,H)   f32
    float* out = (float*)d_out;

    float2* tw = (float2*)d_ws;               // 16384 float2 = 128 KiB
    float2* Kf = tw + FFT_N;                  // 256*16384 float2 = 32 MiB

    twiddle_init<<<FFT_N / 256, 256, 0, stream>>>(tw);
    kfft_kernel<<<H_DIM, NT, 0, stream>>>(k, D, tw, Kf);
    conv_kernel<<<(B_DIM / 2) * H_DIM, NT, 0, stream>>>(u, tw, Kf, out);
}